// Round 3
// baseline (44304.703 us; speedup 1.0000x reference)
//
#include <hip/hip_runtime.h>

#define UNITS  2048
#define IDIM   512
#define TSTEPS 8192

typedef float        v4f __attribute__((ext_vector_type(4)));
typedef float        v2f __attribute__((ext_vector_type(2)));
typedef unsigned int v4u __attribute__((ext_vector_type(4)));

#define POISON 0x7F800000u   // +inf: tanh can never produce it -> zero false-accept

__device__ __forceinline__ float ftanh(float s) {
    // tanh(s) = 1 - 2/(e^{2s}+1);  e^{2s} = 2^{s*2*log2(e)}
    float z = __builtin_amdgcn_exp2f(s * 2.885390081777927f);
    return 1.0f - 2.0f * __builtin_amdgcn_rcpf(z + 1.0f);
}

__device__ __forceinline__ float dot4(float4 a, float4 b) {
    return a.x * b.x + a.y * b.y + a.z * b.z + a.w * b.w;
}

// ---- data-poll primitive (XCD scope, PROVEN mechanism): atomics execute in
// ---- the XCD-local L2 (coherence point), so an OR-with-zero is a pure read
// ---- that always observes the latest L2 contents — unlike sc0 plain loads,
// ---- which livelocked on stale L1 poison two rounds ago.
// ---- Two b64 atomics cover the thread's 16B; one vmcnt wait per retry.
// ---- NOTE gfx950 modifier order: `off offset:N sc0` (offset BEFORE flags).
__device__ __forceinline__ v4u poll4(const unsigned* p) {
    unsigned long long z = 0ull;
    unsigned long long lo, hi;
    asm volatile("global_atomic_or_x2 %0, %2, %3, off sc0\n\t"
                 "global_atomic_or_x2 %1, %2, %3, off offset:8 sc0\n\t"
                 "s_waitcnt vmcnt(0)"
                 : "=&v"(lo), "=&v"(hi)
                 : "v"(p), "v"(z)
                 : "memory");
    v4u r;
    r[0] = (unsigned)lo; r[1] = (unsigned)(lo >> 32);
    r[2] = (unsigned)hi; r[3] = (unsigned)(hi >> 32);
    return r;
}
__device__ __forceinline__ bool any_poison_u(v4u u) {
    bool b = false;
#pragma unroll
    for (int i = 0; i < 4; ++i) b |= (u[i] == POISON);
    return b;
}

// ---- device-scope primitives (fallback kernel, proven in Round 2) ----
__device__ __forceinline__ bool bad4(v4f v) {
    v4u u = __builtin_bit_cast(v4u, v);
    bool b = false;
#pragma unroll
    for (int i = 0; i < 4; ++i) b |= (u[i] == 0u) | (u[i] == 0xAAAAAAAAu);
    return b;
}
__device__ __forceinline__ v4f poll_load_dev(const float4* p) {
    v4f v;
    asm volatile("global_load_dwordx4 %0, %1, off sc1\n\t"
                 "s_waitcnt vmcnt(0)"
                 : "=v"(v) : "v"(p) : "memory");
    return v;
}
__device__ __forceinline__ void pub_store_dev(float4* p, v4f v) {
    asm volatile("global_store_dwordx4 %0, %1, off sc1"
                 :: "v"(p), "v"(v) : "memory");
}

// =======================================================================
// ws layout (u32 index): [0] claim cnt; xin at byte 2048.
// =======================================================================
__global__ void zero_ws(int* ws) {
    int i = threadIdx.x;
    if (i < 512) ws[i] = 0;
}

// Poison d_out with +inf so the scan's data-poll has an unambiguous sentinel.
// 64 MB fill ~ 13-16 us at HBM write BW — negligible vs the scan.
__global__ __launch_bounds__(256)
void poison_ys(v4u* __restrict__ ys) {
    size_t i = (size_t)blockIdx.x * 256 + threadIdx.x;
    v4u p = {POISON, POISON, POISON, POISON};
    ys[i] = p;
}

// =======================================================================
// Kernel 1: xin[t][u] = sum_k x[t][k]*wax[u][k] + ba[u]   (8192 x 2048)
// =======================================================================
#define GT 64
#define GU 64
#define GK 32
__global__ __launch_bounds__(256)
void xin_gemm(const float* __restrict__ x,    // (T, 512)
              const float* __restrict__ wax,  // (U, 512)
              const float* __restrict__ ba,   // (U)
              float* __restrict__ xin)        // (T, U)
{
    __shared__ float Xs[GT][GK + 4];
    __shared__ float Ws[GU][GK + 4];
    const int tid = threadIdx.x;
    const int tx = tid & 15, ty = tid >> 4;
    const int t0 = blockIdx.x * GT, u0 = blockIdx.y * GU;
    float acc[4][4] = {};
    const float4* x4 = (const float4*)x;
    const float4* w4 = (const float4*)wax;
    const int tr = tid >> 2;        // 0..63
    const int kq = tid & 3;         // 0..3

    for (int k0 = 0; k0 < IDIM; k0 += GK) {
        float4 a0 = x4[(size_t)(t0 + tr) * 128 + (k0 >> 2) + kq * 2];
        float4 a1 = x4[(size_t)(t0 + tr) * 128 + (k0 >> 2) + kq * 2 + 1];
        float4 b0 = w4[(size_t)(u0 + tr) * 128 + (k0 >> 2) + kq * 2];
        float4 b1 = w4[(size_t)(u0 + tr) * 128 + (k0 >> 2) + kq * 2 + 1];
        __syncthreads();            // protect previous iteration's LDS reads
        *(float4*)&Xs[tr][kq * 8]     = a0;
        *(float4*)&Xs[tr][kq * 8 + 4] = a1;
        *(float4*)&Ws[tr][kq * 8]     = b0;
        *(float4*)&Ws[tr][kq * 8 + 4] = b1;
        __syncthreads();
#pragma unroll
        for (int k = 0; k < GK; k += 4) {
            float4 xv[4], wv[4];
#pragma unroll
            for (int i = 0; i < 4; ++i) xv[i] = *(float4*)&Xs[ty * 4 + i][k];
#pragma unroll
            for (int j = 0; j < 4; ++j) wv[j] = *(float4*)&Ws[tx * 4 + j][k];
#pragma unroll
            for (int i = 0; i < 4; ++i)
#pragma unroll
                for (int j = 0; j < 4; ++j)
                    acc[i][j] += dot4(xv[i], wv[j]);
        }
    }
    float4 bb = *(const float4*)&ba[u0 + tx * 4];
#pragma unroll
    for (int i = 0; i < 4; ++i) {
        float4 o;
        o.x = acc[i][0] + bb.x; o.y = acc[i][1] + bb.y;
        o.z = acc[i][2] + bb.z; o.w = acc[i][3] + bb.w;
        *(float4*)&xin[(size_t)(t0 + ty * 4 + i) * UNITS + u0 + tx * 4] = o;
    }
}

// =======================================================================
// Kernel 2: single-XCD persistent scan, DIRECT DATA POLLING via L2 atomics:
//  - ys pre-poisoned with +inf (impossible tanh output)
//  - consumer thread tid polls its own 16B of ys[t-1] with 2x
//    global_atomic_or_x2 (OR 0 = pure L2 read, returns old) until all
//    4 dwords are non-poison; per-dword check handles partial arrival
//  - producer: plain stores (write-through L1 -> L2), NO drain, NO flag
//  - barriers: B3' (all waves done reading abuf(t-1), by barrier semantics:
//    arrival at step t's B3' implies step t-1 compute complete) + B2
//    (staging visible block-wide)
// =======================================================================
#define SCAN_LDS_BYTES ((16 * 576 + 576) * 16)   // 147456 + 9216 = 156672

__device__ __forceinline__ float fold2(float a, float b, int d, int lane) {
    float keep = (lane & d) ? b : a;
    float send = (lane & d) ? a : b;
    return keep + __shfl_xor(send, d, 64);
}

__global__ __launch_bounds__(512, 2)
void rnn_scan_xcd(const float* __restrict__ waa,
                  const float* __restrict__ xin,   // (T, U), precomputed
                  float* __restrict__ ys,          // (T, U) == d_out, poisoned
                  int* __restrict__ cnt)
{
    extern __shared__ float4 smem[];
    float4* lws  = smem;              // 16 padded rows x 576 float4
    float4* abuf = smem + 16 * 576;   // 576 float4

    __shared__ int s_slot;
    if (threadIdx.x == 0) {
        unsigned xcc;
        asm volatile("s_getreg_b32 %0, hwreg(HW_REG_XCC_ID)" : "=s"(xcc));
        s_slot = ((xcc & 0xf) == 0) ? atomicAdd(cnt, 1) : -1;   // claim a worker slot
    }
    __syncthreads();
    const int slot = s_slot;
    if (slot < 0 || slot >= 32) return;   // not a worker

    const int tid  = threadIdx.x;
    const int lane = tid & 63;
    const int wave = tid >> 6;
    const int r0   = slot * 64 + wave * 8;      // this wave's 8 rows

    const float4* waa4 = (const float4*)waa;    // (UNITS, 512) float4s
    // 6 register-resident rows (weights live all 8192 steps)
    float4 w[6][8];
#pragma unroll
    for (int r = 0; r < 6; ++r)
#pragma unroll
        for (int k = 0; k < 8; ++k)
            w[r][k] = waa4[(size_t)(r0 + r) * 512 + lane * 8 + k];
    // 2 LDS-resident rows per wave, padded (f -> f + f/8): conflict-free b128
    float4* lw0 = &lws[(wave * 2 + 0) * 576];
    float4* lw1 = &lws[(wave * 2 + 1) * 576];
#pragma unroll
    for (int k = 0; k < 8; ++k) {
        lw0[lane * 9 + k] = waa4[(size_t)(r0 + 6) * 512 + lane * 8 + k];
        lw1[lane * 9 + k] = waa4[(size_t)(r0 + 7) * 512 + lane * 8 + k];
    }
    __syncthreads();

    int budget = 1 << 22;   // sticky safety valve: pathology -> visible fail, not hang

    for (int t = 0; t < TSTEPS; ++t) {
        float xv = xin[(size_t)t * UNITS + r0 + (lane & 7)];   // issued early
        float out;
        if (t == 0) {
            out = ftanh(xv);            // a0 = 0 => no matvec term
        } else {
            // poll own 16B of a(t-1) straight from L2 via atomic-or-0
            const unsigned* src = (const unsigned*)(ys + (size_t)(t - 1) * UNITS)
                                  + 4 * (size_t)tid;
            v4u uv = poll4(src);
            while (any_poison_u(uv) && --budget > 0) {
                __builtin_amdgcn_s_sleep(1);   // ~64 cyc backoff, caps L2 atomic flood
                uv = poll4(src);
            }
            v4f av = __builtin_bit_cast(v4f, uv);

            __syncthreads();            // B3': all waves done reading abuf(t-1)
            abuf[tid + (tid >> 3)] = *(const float4*)&av;
            __syncthreads();            // B2: staging visible block-wide

            // 8-row matvec partials, packed fp32 (v_pk_fma_f32)
            v2f acc2[8];
#pragma unroll
            for (int r = 0; r < 8; ++r) acc2[r] = (v2f){0.f, 0.f};
            const float4* ab = &abuf[lane * 9];
            const float4* l0 = &lw0[lane * 9];
            const float4* l1 = &lw1[lane * 9];
#pragma unroll
            for (int k = 0; k < 8; ++k) {
                float4 a4 = ab[k];
                v2f alo = {a4.x, a4.y}, ahi = {a4.z, a4.w};
#pragma unroll
                for (int r = 0; r < 6; ++r) {
                    v2f wlo = {w[r][k].x, w[r][k].y};
                    v2f whi = {w[r][k].z, w[r][k].w};
                    acc2[r] += alo * wlo;
                    acc2[r] += ahi * whi;
                }
                float4 u0 = l0[k], u1 = l1[k];
                acc2[6] += alo * (v2f){u0.x, u0.y};
                acc2[6] += ahi * (v2f){u0.z, u0.w};
                acc2[7] += alo * (v2f){u1.x, u1.y};
                acc2[7] += ahi * (v2f){u1.z, u1.w};
            }
            float acc[8];
#pragma unroll
            for (int r = 0; r < 8; ++r) acc[r] = acc2[r].x + acc2[r].y;

            // 8-row wave reduction: 3 fold rounds -> lane holds row (lane&7)
            float f4[4], f2[2], f1;
#pragma unroll
            for (int r = 0; r < 4; ++r) f4[r] = fold2(acc[2 * r], acc[2 * r + 1], 1, lane);
#pragma unroll
            for (int r = 0; r < 2; ++r) f2[r] = fold2(f4[2 * r], f4[2 * r + 1], 2, lane);
            f1 = fold2(f2[0], f2[1], 4, lane);
            f1 += __shfl_xor(f1, 8, 64);
            f1 += __shfl_xor(f1, 16, 64);
            f1 += __shfl_xor(f1, 32, 64);
            out = ftanh(f1 + xv);
        }
        if (lane < 8)
            ys[(size_t)t * UNITS + r0 + lane] = out;   // plain store; write-through
        // L1 -> lands in XCD L2 at its own pace. Consumers poll the data itself
        // at the coherence point, so no vmcnt drain / flag / release barrier.
    }
}

// =======================================================================
// Fallback (Round-2 kernel, device-scope sync): used only if ws too small.
// NOTE: unchanged — it does NOT use the inf-poison protocol.
// =======================================================================
__global__ __launch_bounds__(512, 2)
void rnn_scan_fb(const float* __restrict__ x,
                 const float* __restrict__ waa,
                 const float* __restrict__ wax,
                 const float* __restrict__ ba,
                 float* __restrict__ ys)
{
    __shared__ float4 fabuf[2][576];
    const int tid  = threadIdx.x;
    const int lane = tid & 63;
    const int wave = tid >> 6;
    const int r0   = blockIdx.x * 32 + wave * 4;

    const float4* waa4 = (const float4*)waa;
    const float4* wax4 = (const float4*)wax;
    float4 w[4][8]; float4 wx[4][2]; float bav[4];
#pragma unroll
    for (int r = 0; r < 4; ++r) {
#pragma unroll
        for (int k = 0; k < 8; ++k) w[r][k] = waa4[(size_t)(r0 + r) * 512 + lane * 8 + k];
#pragma unroll
        for (int k = 0; k < 2; ++k) wx[r][k] = wax4[(size_t)(r0 + r) * 128 + lane * 2 + k];
        bav[r] = ba[r0 + r];
    }
    const float4* x4 = (const float4*)x;
    int budget = 1 << 22;

    for (int t = 0; t < TSTEPS; ++t) {
        float4 xa = x4[(size_t)t * 128 + lane * 2];
        float4 xb = x4[(size_t)t * 128 + lane * 2 + 1];
        if (t > 0) {
            const float4* src = (const float4*)(ys + (size_t)(t - 1) * UNITS) + tid;
            v4f av = poll_load_dev(src);
            while (bad4(av) && --budget > 0) av = poll_load_dev(src);
            fabuf[t & 1][tid + (tid >> 3)] = *(const float4*)&av;
        }
        float s[4];
#pragma unroll
        for (int r = 0; r < 4; ++r)
            s[r] = dot4(xa, wx[r][0]) + dot4(xb, wx[r][1]);
        if (t > 0) {
            __syncthreads();
            const float4* ab = &fabuf[t & 1][lane * 9];
#pragma unroll
            for (int k = 0; k < 8; ++k) {
                float4 av = ab[k];
#pragma unroll
                for (int r = 0; r < 4; ++r) s[r] += dot4(av, w[r][k]);
            }
        }
#pragma unroll
        for (int m = 32; m >= 1; m >>= 1)
#pragma unroll
            for (int r = 0; r < 4; ++r) s[r] += __shfl_xor(s[r], m, 64);
        if (lane == 0) {
            v4f o;
#pragma unroll
            for (int r = 0; r < 4; ++r) o[r] = ftanh(s[r] + bav[r]);
            pub_store_dev((float4*)(ys + (size_t)t * UNITS + r0), o);
        }
    }
}

extern "C" void kernel_launch(void* const* d_in, const int* in_sizes, int n_in,
                              void* d_out, int out_size, void* d_ws, size_t ws_size,
                              hipStream_t stream) {
    const float* x   = (const float*)d_in[0];   // (1, 8192, 512)
    const float* waa = (const float*)d_in[1];   // (2048, 2048)
    const float* wax = (const float*)d_in[2];   // (2048, 512)
    const float* ba  = (const float*)d_in[3];   // (2048, 1)
    float* ys = (float*)d_out;                  // (1, 8192, 2048)

    const size_t xin_off = 2048;                // bytes; after cnt area
    const size_t need = xin_off + (size_t)TSTEPS * UNITS * sizeof(float);
    if (ws_size >= need) {
        (void)hipFuncSetAttribute(reinterpret_cast<const void*>(rnn_scan_xcd),
                                  hipFuncAttributeMaxDynamicSharedMemorySize,
                                  SCAN_LDS_BYTES);
        int*   wsi = (int*)d_ws;
        float* xin = (float*)((char*)d_ws + xin_off);
        hipLaunchKernelGGL(zero_ws, dim3(1), dim3(512), 0, stream, wsi);
        // re-poison d_out every launch: (T*U)/4 uint4s, 256 thr/blk
        hipLaunchKernelGGL(poison_ys, dim3((TSTEPS * (size_t)UNITS) / (4 * 256)),
                           dim3(256), 0, stream, (v4u*)ys);
        hipLaunchKernelGGL(xin_gemm, dim3(TSTEPS / GT, UNITS / GU), dim3(256), 0, stream,
                           x, wax, ba, xin);
        hipLaunchKernelGGL(rnn_scan_xcd, dim3(1024), dim3(512), SCAN_LDS_BYTES, stream,
                           waa, xin, ys, wsi);
    } else {
        hipLaunchKernelGGL(rnn_scan_fb, dim3(64), dim3(512), 0, stream,
                           x, waa, wax, ba, ys);
    }
}

// Round 4
// 14562.491 us; speedup vs baseline: 3.0424x; 3.0424x over previous
//
#include <hip/hip_runtime.h>

#define UNITS  2048
#define IDIM   512
#define TSTEPS 8192

typedef float        v4f __attribute__((ext_vector_type(4)));
typedef float        v2f __attribute__((ext_vector_type(2)));
typedef unsigned int v4u __attribute__((ext_vector_type(4)));

#define POISON 0x7F800000u   // +inf: tanh can never produce it -> zero false-accept

__device__ __forceinline__ float ftanh(float s) {
    // tanh(s) = 1 - 2/(e^{2s}+1);  e^{2s} = 2^{s*2*log2(e)}
    float z = __builtin_amdgcn_exp2f(s * 2.885390081777927f);
    return 1.0f - 2.0f * __builtin_amdgcn_rcpf(z + 1.0f);
}

__device__ __forceinline__ float dot4(float4 a, float4 b) {
    return a.x * b.x + a.y * b.y + a.z * b.z + a.w * b.w;
}

// ---- data-poll primitive: sc1 plain load. PROVEN (fallback kernel) to
// ---- bypass stale L1 AND observe dirty lines in the local XCD L2.
// ---- Read-only: no line dirtying, no TCC serialization, no HBM writeback
// ---- (Round 3's atomic-or polls caused 6.4 GB of HBM writes — refuted).
__device__ __forceinline__ v4f poll_load_sc1(const float4* p) {
    v4f v;
    asm volatile("global_load_dwordx4 %0, %1, off sc1\n\t"
                 "s_waitcnt vmcnt(0)"
                 : "=v"(v) : "v"(p) : "memory");
    return v;
}
__device__ __forceinline__ bool any_poison(v4f v) {
    v4u u = __builtin_bit_cast(v4u, v);
    bool b = false;
#pragma unroll
    for (int i = 0; i < 4; ++i) b |= (u[i] == POISON);
    return b;
}

// ---- device-scope primitives (fallback kernel, proven in Round 2) ----
__device__ __forceinline__ bool bad4(v4f v) {
    v4u u = __builtin_bit_cast(v4u, v);
    bool b = false;
#pragma unroll
    for (int i = 0; i < 4; ++i) b |= (u[i] == 0u) | (u[i] == 0xAAAAAAAAu);
    return b;
}
__device__ __forceinline__ void pub_store_dev(float4* p, v4f v) {
    asm volatile("global_store_dwordx4 %0, %1, off sc1"
                 :: "v"(p), "v"(v) : "memory");
}

// =======================================================================
// ws layout (u32 index): [0] claim cnt; xin at byte 2048.
// =======================================================================
__global__ void zero_ws(int* ws) {
    int i = threadIdx.x;
    if (i < 512) ws[i] = 0;
}

// Poison d_out with +inf so the scan's data-poll has an unambiguous sentinel.
// Kernel-boundary L2 writeback makes the poison globally visible before the
// scan starts (verified: Round 3 passed with this exact pre-pass).
__global__ __launch_bounds__(256)
void poison_ys(v4u* __restrict__ ys) {
    size_t i = (size_t)blockIdx.x * 256 + threadIdx.x;
    v4u p = {POISON, POISON, POISON, POISON};
    ys[i] = p;
}

// =======================================================================
// Kernel 1: xin[t][u] = sum_k x[t][k]*wax[u][k] + ba[u]   (8192 x 2048)
// =======================================================================
#define GT 64
#define GU 64
#define GK 32
__global__ __launch_bounds__(256)
void xin_gemm(const float* __restrict__ x,    // (T, 512)
              const float* __restrict__ wax,  // (U, 512)
              const float* __restrict__ ba,   // (U)
              float* __restrict__ xin)        // (T, U)
{
    __shared__ float Xs[GT][GK + 4];
    __shared__ float Ws[GU][GK + 4];
    const int tid = threadIdx.x;
    const int tx = tid & 15, ty = tid >> 4;
    const int t0 = blockIdx.x * GT, u0 = blockIdx.y * GU;
    float acc[4][4] = {};
    const float4* x4 = (const float4*)x;
    const float4* w4 = (const float4*)wax;
    const int tr = tid >> 2;        // 0..63
    const int kq = tid & 3;         // 0..3

    for (int k0 = 0; k0 < IDIM; k0 += GK) {
        float4 a0 = x4[(size_t)(t0 + tr) * 128 + (k0 >> 2) + kq * 2];
        float4 a1 = x4[(size_t)(t0 + tr) * 128 + (k0 >> 2) + kq * 2 + 1];
        float4 b0 = w4[(size_t)(u0 + tr) * 128 + (k0 >> 2) + kq * 2];
        float4 b1 = w4[(size_t)(u0 + tr) * 128 + (k0 >> 2) + kq * 2 + 1];
        __syncthreads();            // protect previous iteration's LDS reads
        *(float4*)&Xs[tr][kq * 8]     = a0;
        *(float4*)&Xs[tr][kq * 8 + 4] = a1;
        *(float4*)&Ws[tr][kq * 8]     = b0;
        *(float4*)&Ws[tr][kq * 8 + 4] = b1;
        __syncthreads();
#pragma unroll
        for (int k = 0; k < GK; k += 4) {
            float4 xv[4], wv[4];
#pragma unroll
            for (int i = 0; i < 4; ++i) xv[i] = *(float4*)&Xs[ty * 4 + i][k];
#pragma unroll
            for (int j = 0; j < 4; ++j) wv[j] = *(float4*)&Ws[tx * 4 + j][k];
#pragma unroll
            for (int i = 0; i < 4; ++i)
#pragma unroll
                for (int j = 0; j < 4; ++j)
                    acc[i][j] += dot4(xv[i], wv[j]);
        }
    }
    float4 bb = *(const float4*)&ba[u0 + tx * 4];
#pragma unroll
    for (int i = 0; i < 4; ++i) {
        float4 o;
        o.x = acc[i][0] + bb.x; o.y = acc[i][1] + bb.y;
        o.z = acc[i][2] + bb.z; o.w = acc[i][3] + bb.w;
        *(float4*)&xin[(size_t)(t0 + ty * 4 + i) * UNITS + u0 + tx * 4] = o;
    }
}

// =======================================================================
// Kernel 2: single-XCD persistent scan, DIRECT DATA POLLING via sc1 loads:
//  - ys pre-poisoned with +inf (impossible tanh output)
//  - consumer thread tid poll-loads its own 16B of ys[t-1] with
//    global_load_dwordx4 sc1 (L1-bypass, reads XCD L2 incl. dirty lines)
//    until all 4 dwords are non-poison; per-dword check handles partial
//    arrival (protocol correctness proven by Round 3's pass)
//  - producer: plain stores (write-through L1 -> L2), NO drain, NO flag
//  - barriers: B3' (all waves done reading abuf(t-1)) + B2 (staging
//    visible block-wide)
// =======================================================================
#define SCAN_LDS_BYTES ((16 * 576 + 576) * 16)   // 147456 + 9216 = 156672

__device__ __forceinline__ float fold2(float a, float b, int d, int lane) {
    float keep = (lane & d) ? b : a;
    float send = (lane & d) ? a : b;
    return keep + __shfl_xor(send, d, 64);
}

__global__ __launch_bounds__(512, 2)
void rnn_scan_xcd(const float* __restrict__ waa,
                  const float* __restrict__ xin,   // (T, U), precomputed
                  float* __restrict__ ys,          // (T, U) == d_out, poisoned
                  int* __restrict__ cnt)
{
    extern __shared__ float4 smem[];
    float4* lws  = smem;              // 16 padded rows x 576 float4
    float4* abuf = smem + 16 * 576;   // 576 float4

    __shared__ int s_slot;
    if (threadIdx.x == 0) {
        unsigned xcc;
        asm volatile("s_getreg_b32 %0, hwreg(HW_REG_XCC_ID)" : "=s"(xcc));
        s_slot = ((xcc & 0xf) == 0) ? atomicAdd(cnt, 1) : -1;   // claim a worker slot
    }
    __syncthreads();
    const int slot = s_slot;
    if (slot < 0 || slot >= 32) return;   // not a worker

    const int tid  = threadIdx.x;
    const int lane = tid & 63;
    const int wave = tid >> 6;
    const int r0   = slot * 64 + wave * 8;      // this wave's 8 rows

    const float4* waa4 = (const float4*)waa;    // (UNITS, 512) float4s
    // 6 register-resident rows (weights live all 8192 steps)
    float4 w[6][8];
#pragma unroll
    for (int r = 0; r < 6; ++r)
#pragma unroll
        for (int k = 0; k < 8; ++k)
            w[r][k] = waa4[(size_t)(r0 + r) * 512 + lane * 8 + k];
    // 2 LDS-resident rows per wave, padded (f -> f + f/8): conflict-free b128
    float4* lw0 = &lws[(wave * 2 + 0) * 576];
    float4* lw1 = &lws[(wave * 2 + 1) * 576];
#pragma unroll
    for (int k = 0; k < 8; ++k) {
        lw0[lane * 9 + k] = waa4[(size_t)(r0 + 6) * 512 + lane * 8 + k];
        lw1[lane * 9 + k] = waa4[(size_t)(r0 + 7) * 512 + lane * 8 + k];
    }
    __syncthreads();

    int budget = 1 << 22;   // sticky safety valve: pathology -> visible fail, not hang

    for (int t = 0; t < TSTEPS; ++t) {
        float xv = xin[(size_t)t * UNITS + r0 + (lane & 7)];   // issued early
        float out;
        if (t == 0) {
            out = ftanh(xv);            // a0 = 0 => no matvec term
        } else {
            // poll own 16B of a(t-1): sc1 load straight from XCD L2
            const float4* src = (const float4*)(ys + (size_t)(t - 1) * UNITS) + tid;
            v4f av = poll_load_sc1(src);
            while (any_poison(av) && --budget > 0) av = poll_load_sc1(src);

            __syncthreads();            // B3': all waves done reading abuf(t-1)
            abuf[tid + (tid >> 3)] = *(const float4*)&av;
            __syncthreads();            // B2: staging visible block-wide

            // 8-row matvec partials, packed fp32 (v_pk_fma_f32)
            v2f acc2[8];
#pragma unroll
            for (int r = 0; r < 8; ++r) acc2[r] = (v2f){0.f, 0.f};
            const float4* ab = &abuf[lane * 9];
            const float4* l0 = &lw0[lane * 9];
            const float4* l1 = &lw1[lane * 9];
#pragma unroll
            for (int k = 0; k < 8; ++k) {
                float4 a4 = ab[k];
                v2f alo = {a4.x, a4.y}, ahi = {a4.z, a4.w};
#pragma unroll
                for (int r = 0; r < 6; ++r) {
                    v2f wlo = {w[r][k].x, w[r][k].y};
                    v2f whi = {w[r][k].z, w[r][k].w};
                    acc2[r] += alo * wlo;
                    acc2[r] += ahi * whi;
                }
                float4 u0 = l0[k], u1 = l1[k];
                acc2[6] += alo * (v2f){u0.x, u0.y};
                acc2[6] += ahi * (v2f){u0.z, u0.w};
                acc2[7] += alo * (v2f){u1.x, u1.y};
                acc2[7] += ahi * (v2f){u1.z, u1.w};
            }
            float acc[8];
#pragma unroll
            for (int r = 0; r < 8; ++r) acc[r] = acc2[r].x + acc2[r].y;

            // 8-row wave reduction: 3 fold rounds -> lane holds row (lane&7)
            float f4[4], f2[2], f1;
#pragma unroll
            for (int r = 0; r < 4; ++r) f4[r] = fold2(acc[2 * r], acc[2 * r + 1], 1, lane);
#pragma unroll
            for (int r = 0; r < 2; ++r) f2[r] = fold2(f4[2 * r], f4[2 * r + 1], 2, lane);
            f1 = fold2(f2[0], f2[1], 4, lane);
            f1 += __shfl_xor(f1, 8, 64);
            f1 += __shfl_xor(f1, 16, 64);
            f1 += __shfl_xor(f1, 32, 64);
            out = ftanh(f1 + xv);
        }
        if (lane < 8)
            ys[(size_t)t * UNITS + r0 + lane] = out;   // plain store; write-through
        // L1 -> lands in XCD L2 at its own pace. Consumers poll the data itself
        // with sc1 loads, so no vmcnt drain / flag / release barrier.
    }
}

// =======================================================================
// Fallback (Round-2 kernel, device-scope sync): used only if ws too small.
// NOTE: unchanged — it does NOT use the inf-poison protocol.
// =======================================================================
__global__ __launch_bounds__(512, 2)
void rnn_scan_fb(const float* __restrict__ x,
                 const float* __restrict__ waa,
                 const float* __restrict__ wax,
                 const float* __restrict__ ba,
                 float* __restrict__ ys)
{
    __shared__ float4 fabuf[2][576];
    const int tid  = threadIdx.x;
    const int lane = tid & 63;
    const int wave = tid >> 6;
    const int r0   = blockIdx.x * 32 + wave * 4;

    const float4* waa4 = (const float4*)waa;
    const float4* wax4 = (const float4*)wax;
    float4 w[4][8]; float4 wx[4][2]; float bav[4];
#pragma unroll
    for (int r = 0; r < 4; ++r) {
#pragma unroll
        for (int k = 0; k < 8; ++k) w[r][k] = waa4[(size_t)(r0 + r) * 512 + lane * 8 + k];
#pragma unroll
        for (int k = 0; k < 2; ++k) wx[r][k] = wax4[(size_t)(r0 + r) * 128 + lane * 2 + k];
        bav[r] = ba[r0 + r];
    }
    const float4* x4 = (const float4*)x;
    int budget = 1 << 22;

    for (int t = 0; t < TSTEPS; ++t) {
        float4 xa = x4[(size_t)t * 128 + lane * 2];
        float4 xb = x4[(size_t)t * 128 + lane * 2 + 1];
        if (t > 0) {
            const float4* src = (const float4*)(ys + (size_t)(t - 1) * UNITS) + tid;
            v4f av = poll_load_sc1(src);
            while (bad4(av) && --budget > 0) av = poll_load_sc1(src);
            fabuf[t & 1][tid + (tid >> 3)] = *(const float4*)&av;
        }
        float s[4];
#pragma unroll
        for (int r = 0; r < 4; ++r)
            s[r] = dot4(xa, wx[r][0]) + dot4(xb, wx[r][1]);
        if (t > 0) {
            __syncthreads();
            const float4* ab = &fabuf[t & 1][lane * 9];
#pragma unroll
            for (int k = 0; k < 8; ++k) {
                float4 av = ab[k];
#pragma unroll
                for (int r = 0; r < 4; ++r) s[r] += dot4(av, w[r][k]);
            }
        }
#pragma unroll
        for (int m = 32; m >= 1; m >>= 1)
#pragma unroll
            for (int r = 0; r < 4; ++r) s[r] += __shfl_xor(s[r], m, 64);
        if (lane == 0) {
            v4f o;
#pragma unroll
            for (int r = 0; r < 4; ++r) o[r] = ftanh(s[r] + bav[r]);
            pub_store_dev((float4*)(ys + (size_t)t * UNITS + r0), o);
        }
    }
}

extern "C" void kernel_launch(void* const* d_in, const int* in_sizes, int n_in,
                              void* d_out, int out_size, void* d_ws, size_t ws_size,
                              hipStream_t stream) {
    const float* x   = (const float*)d_in[0];   // (1, 8192, 512)
    const float* waa = (const float*)d_in[1];   // (2048, 2048)
    const float* wax = (const float*)d_in[2];   // (2048, 512)
    const float* ba  = (const float*)d_in[3];   // (2048, 1)
    float* ys = (float*)d_out;                  // (1, 8192, 2048)

    const size_t xin_off = 2048;                // bytes; after cnt area
    const size_t need = xin_off + (size_t)TSTEPS * UNITS * sizeof(float);
    if (ws_size >= need) {
        (void)hipFuncSetAttribute(reinterpret_cast<const void*>(rnn_scan_xcd),
                                  hipFuncAttributeMaxDynamicSharedMemorySize,
                                  SCAN_LDS_BYTES);
        int*   wsi = (int*)d_ws;
        float* xin = (float*)((char*)d_ws + xin_off);
        hipLaunchKernelGGL(zero_ws, dim3(1), dim3(512), 0, stream, wsi);
        // re-poison d_out every launch: (T*U)/4 uint4s, 256 thr/blk
        hipLaunchKernelGGL(poison_ys, dim3((TSTEPS * (size_t)UNITS) / (4 * 256)),
                           dim3(256), 0, stream, (v4u*)ys);
        hipLaunchKernelGGL(xin_gemm, dim3(TSTEPS / GT, UNITS / GU), dim3(256), 0, stream,
                           x, wax, ba, xin);
        hipLaunchKernelGGL(rnn_scan_xcd, dim3(1024), dim3(512), SCAN_LDS_BYTES, stream,
                           waa, xin, ys, wsi);
    } else {
        hipLaunchKernelGGL(rnn_scan_fb, dim3(64), dim3(512), 0, stream,
                           x, waa, wax, ba, ys);
    }
}

// Round 5
// 14385.320 us; speedup vs baseline: 3.0799x; 1.0123x over previous
//
#include <hip/hip_runtime.h>

#define UNITS  2048
#define IDIM   512
#define TSTEPS 8192

typedef float        v4f __attribute__((ext_vector_type(4)));
typedef float        v2f __attribute__((ext_vector_type(2)));
typedef unsigned int v4u __attribute__((ext_vector_type(4)));

#define POISON 0x7F800000u   // +inf: tanh can never produce it -> zero false-accept

__device__ __forceinline__ float ftanh(float s) {
    // tanh(s) = 1 - 2/(e^{2s}+1);  e^{2s} = 2^{s*2*log2(e)}
    float z = __builtin_amdgcn_exp2f(s * 2.885390081777927f);
    return 1.0f - 2.0f * __builtin_amdgcn_rcpf(z + 1.0f);
}

__device__ __forceinline__ float dot4(float4 a, float4 b) {
    return a.x * b.x + a.y * b.y + a.z * b.z + a.w * b.w;
}

// ---- data-poll primitive: sc1 plain load. PROVEN (Round 4) to bypass stale
// ---- L1 AND observe dirty lines in the local XCD L2. Read-only: no line
// ---- dirtying, no TCC serialization (Round 3's atomic polls: 6.4 GB HBM
// ---- writes — refuted).
__device__ __forceinline__ v4f poll_load_sc1(const float4* p) {
    v4f v;
    asm volatile("global_load_dwordx4 %0, %1, off sc1\n\t"
                 "s_waitcnt vmcnt(0)"
                 : "=v"(v) : "v"(p) : "memory");
    return v;
}
__device__ __forceinline__ bool any_poison(v4f v) {
    v4u u = __builtin_bit_cast(v4u, v);
    bool b = false;
#pragma unroll
    for (int i = 0; i < 4; ++i) b |= (u[i] == POISON);
    return b;
}

// ---- device-scope primitives (fallback kernel, proven in prior session) ----
__device__ __forceinline__ bool bad4(v4f v) {
    v4u u = __builtin_bit_cast(v4u, v);
    bool b = false;
#pragma unroll
    for (int i = 0; i < 4; ++i) b |= (u[i] == 0u) | (u[i] == 0xAAAAAAAAu);
    return b;
}
__device__ __forceinline__ void pub_store_dev(float4* p, v4f v) {
    asm volatile("global_store_dwordx4 %0, %1, off sc1"
                 :: "v"(p), "v"(v) : "memory");
}

// =======================================================================
// ws layout (u32 index): [0] claim cnt; xin at byte 2048.
// =======================================================================
__global__ void zero_ws(int* ws) {
    int i = threadIdx.x;
    if (i < 512) ws[i] = 0;
}

// Poison d_out with +inf so the scan's data-poll has an unambiguous sentinel.
__global__ __launch_bounds__(256)
void poison_ys(v4u* __restrict__ ys) {
    size_t i = (size_t)blockIdx.x * 256 + threadIdx.x;
    v4u p = {POISON, POISON, POISON, POISON};
    ys[i] = p;
}

// =======================================================================
// Kernel 1: xin[t][u] = sum_k x[t][k]*wax[u][k] + ba[u]   (8192 x 2048)
// =======================================================================
#define GT 64
#define GU 64
#define GK 32
__global__ __launch_bounds__(256)
void xin_gemm(const float* __restrict__ x,    // (T, 512)
              const float* __restrict__ wax,  // (U, 512)
              const float* __restrict__ ba,   // (U)
              float* __restrict__ xin)        // (T, U)
{
    __shared__ float Xs[GT][GK + 4];
    __shared__ float Ws[GU][GK + 4];
    const int tid = threadIdx.x;
    const int tx = tid & 15, ty = tid >> 4;
    const int t0 = blockIdx.x * GT, u0 = blockIdx.y * GU;
    float acc[4][4] = {};
    const float4* x4 = (const float4*)x;
    const float4* w4 = (const float4*)wax;
    const int tr = tid >> 2;        // 0..63
    const int kq = tid & 3;         // 0..3

    for (int k0 = 0; k0 < IDIM; k0 += GK) {
        float4 a0 = x4[(size_t)(t0 + tr) * 128 + (k0 >> 2) + kq * 2];
        float4 a1 = x4[(size_t)(t0 + tr) * 128 + (k0 >> 2) + kq * 2 + 1];
        float4 b0 = w4[(size_t)(u0 + tr) * 128 + (k0 >> 2) + kq * 2];
        float4 b1 = w4[(size_t)(u0 + tr) * 128 + (k0 >> 2) + kq * 2 + 1];
        __syncthreads();            // protect previous iteration's LDS reads
        *(float4*)&Xs[tr][kq * 8]     = a0;
        *(float4*)&Xs[tr][kq * 8 + 4] = a1;
        *(float4*)&Ws[tr][kq * 8]     = b0;
        *(float4*)&Ws[tr][kq * 8 + 4] = b1;
        __syncthreads();
#pragma unroll
        for (int k = 0; k < GK; k += 4) {
            float4 xv[4], wv[4];
#pragma unroll
            for (int i = 0; i < 4; ++i) xv[i] = *(float4*)&Xs[ty * 4 + i][k];
#pragma unroll
            for (int j = 0; j < 4; ++j) wv[j] = *(float4*)&Ws[tx * 4 + j][k];
#pragma unroll
            for (int i = 0; i < 4; ++i)
#pragma unroll
                for (int j = 0; j < 4; ++j)
                    acc[i][j] += dot4(xv[i], wv[j]);
        }
    }
    float4 bb = *(const float4*)&ba[u0 + tx * 4];
#pragma unroll
    for (int i = 0; i < 4; ++i) {
        float4 o;
        o.x = acc[i][0] + bb.x; o.y = acc[i][1] + bb.y;
        o.z = acc[i][2] + bb.z; o.w = acc[i][3] + bb.w;
        *(float4*)&xin[(size_t)(t0 + ty * 4 + i) * UNITS + u0 + tx * 4] = o;
    }
}

// =======================================================================
// Kernel 2: single-XCD persistent scan, direct sc1 data-polling.
// Round-5 change: xin[t] is REGISTER-PREFETCHED one step ahead, issued
// only AFTER the polls succeed. Previously the xin load (HBM cold miss,
// ~900 cy; FETCH_SIZE shows xin streams from HBM) was issued before the
// poll and the poll's vmcnt(0) — which drains in issue order — serialized
// that miss into every step. Now nothing old is outstanding at poll time
// except last step's stores/prefetch (a full compute phase old).
// =======================================================================
#define SCAN_LDS_BYTES ((16 * 576 + 576) * 16)   // 147456 + 9216 = 156672

__device__ __forceinline__ float fold2(float a, float b, int d, int lane) {
    float keep = (lane & d) ? b : a;
    float send = (lane & d) ? a : b;
    return keep + __shfl_xor(send, d, 64);
}

__global__ __launch_bounds__(512, 2)
void rnn_scan_xcd(const float* __restrict__ waa,
                  const float* __restrict__ xin,   // (T, U), precomputed
                  float* __restrict__ ys,          // (T, U) == d_out, poisoned
                  int* __restrict__ cnt)
{
    extern __shared__ float4 smem[];
    float4* lws  = smem;              // 16 padded rows x 576 float4
    float4* abuf = smem + 16 * 576;   // 576 float4

    __shared__ int s_slot;
    if (threadIdx.x == 0) {
        unsigned xcc;
        asm volatile("s_getreg_b32 %0, hwreg(HW_REG_XCC_ID)" : "=s"(xcc));
        s_slot = ((xcc & 0xf) == 0) ? atomicAdd(cnt, 1) : -1;   // claim a worker slot
    }
    __syncthreads();
    const int slot = s_slot;
    if (slot < 0 || slot >= 32) return;   // not a worker

    const int tid  = threadIdx.x;
    const int lane = tid & 63;
    const int wave = tid >> 6;
    const int r0   = slot * 64 + wave * 8;      // this wave's 8 rows

    const float4* waa4 = (const float4*)waa;    // (UNITS, 512) float4s
    // 6 register-resident rows (weights live all 8192 steps)
    float4 w[6][8];
#pragma unroll
    for (int r = 0; r < 6; ++r)
#pragma unroll
        for (int k = 0; k < 8; ++k)
            w[r][k] = waa4[(size_t)(r0 + r) * 512 + lane * 8 + k];
    // 2 LDS-resident rows per wave, padded (f -> f + f/8): conflict-free b128
    float4* lw0 = &lws[(wave * 2 + 0) * 576];
    float4* lw1 = &lws[(wave * 2 + 1) * 576];
#pragma unroll
    for (int k = 0; k < 8; ++k) {
        lw0[lane * 9 + k] = waa4[(size_t)(r0 + 6) * 512 + lane * 8 + k];
        lw1[lane * 9 + k] = waa4[(size_t)(r0 + 7) * 512 + lane * 8 + k];
    }
    __syncthreads();

    int budget = 1 << 22;   // sticky safety valve: pathology -> visible fail, not hang

    const size_t xoff = (size_t)(r0 + (lane & 7));
    float xv = xin[xoff];             // t=0 value (waits naturally, once)

    for (int t = 0; t < TSTEPS; ++t) {
        float out;
        float xv_next;
        if (t == 0) {
            out = ftanh(xv);          // a0 = 0 => no matvec term
            xv_next = xin[(size_t)1 * UNITS + xoff];
        } else {
            // poll own 16B of a(t-1): sc1 load straight from XCD L2.
            // Nothing HBM-cold is outstanding here (prefetch is a full
            // compute phase old), so vmcnt(0) waits only on the poll itself.
            const float4* src = (const float4*)(ys + (size_t)(t - 1) * UNITS) + tid;
            v4f av = poll_load_sc1(src);
            while (any_poison(av) && --budget > 0) av = poll_load_sc1(src);

            // issue next step's xin prefetch NOW: resolves during the
            // ~2000 cy compute phase below, off the critical path.
            {
                const int tn = (t + 1 < TSTEPS) ? (t + 1) : t;   // stay in bounds
                xv_next = xin[(size_t)tn * UNITS + xoff];
            }

            __syncthreads();            // B3': all waves done reading abuf(t-1)
            abuf[tid + (tid >> 3)] = *(const float4*)&av;
            __syncthreads();            // B2: staging visible block-wide

            // 8-row matvec partials, packed fp32 (v_pk_fma_f32)
            v2f acc2[8];
#pragma unroll
            for (int r = 0; r < 8; ++r) acc2[r] = (v2f){0.f, 0.f};
            const float4* ab = &abuf[lane * 9];
            const float4* l0 = &lw0[lane * 9];
            const float4* l1 = &lw1[lane * 9];
#pragma unroll
            for (int k = 0; k < 8; ++k) {
                float4 a4 = ab[k];
                v2f alo = {a4.x, a4.y}, ahi = {a4.z, a4.w};
#pragma unroll
                for (int r = 0; r < 6; ++r) {
                    v2f wlo = {w[r][k].x, w[r][k].y};
                    v2f whi = {w[r][k].z, w[r][k].w};
                    acc2[r] += alo * wlo;
                    acc2[r] += ahi * whi;
                }
                float4 u0 = l0[k], u1 = l1[k];
                acc2[6] += alo * (v2f){u0.x, u0.y};
                acc2[6] += ahi * (v2f){u0.z, u0.w};
                acc2[7] += alo * (v2f){u1.x, u1.y};
                acc2[7] += ahi * (v2f){u1.z, u1.w};
            }
            float acc[8];
#pragma unroll
            for (int r = 0; r < 8; ++r) acc[r] = acc2[r].x + acc2[r].y;

            // 8-row wave reduction: 3 fold rounds -> lane holds row (lane&7)
            float f4[4], f2[2], f1;
#pragma unroll
            for (int r = 0; r < 4; ++r) f4[r] = fold2(acc[2 * r], acc[2 * r + 1], 1, lane);
#pragma unroll
            for (int r = 0; r < 2; ++r) f2[r] = fold2(f4[2 * r], f4[2 * r + 1], 2, lane);
            f1 = fold2(f2[0], f2[1], 4, lane);
            f1 += __shfl_xor(f1, 8, 64);
            f1 += __shfl_xor(f1, 16, 64);
            f1 += __shfl_xor(f1, 32, 64);
            out = ftanh(f1 + xv);
        }
        if (lane < 8)
            ys[(size_t)t * UNITS + r0 + lane] = out;   // plain store; write-through
        // L1 -> lands in XCD L2 at its own pace. Consumers poll the data
        // itself with sc1 loads, so no vmcnt drain / flag / release barrier.
        xv = xv_next;
    }
}

// =======================================================================
// Fallback (device-scope sync, proven in prior session): used only if ws
// too small. NOTE: it does NOT use the inf-poison protocol.
// =======================================================================
__global__ __launch_bounds__(512, 2)
void rnn_scan_fb(const float* __restrict__ x,
                 const float* __restrict__ waa,
                 const float* __restrict__ wax,
                 const float* __restrict__ ba,
                 float* __restrict__ ys)
{
    __shared__ float4 fabuf[2][576];
    const int tid  = threadIdx.x;
    const int lane = tid & 63;
    const int wave = tid >> 6;
    const int r0   = blockIdx.x * 32 + wave * 4;

    const float4* waa4 = (const float4*)waa;
    const float4* wax4 = (const float4*)wax;
    float4 w[4][8]; float4 wx[4][2]; float bav[4];
#pragma unroll
    for (int r = 0; r < 4; ++r) {
#pragma unroll
        for (int k = 0; k < 8; ++k) w[r][k] = waa4[(size_t)(r0 + r) * 512 + lane * 8 + k];
#pragma unroll
        for (int k = 0; k < 2; ++k) wx[r][k] = wax4[(size_t)(r0 + r) * 128 + lane * 2 + k];
        bav[r] = ba[r0 + r];
    }
    const float4* x4 = (const float4*)x;
    int budget = 1 << 22;

    for (int t = 0; t < TSTEPS; ++t) {
        float4 xa = x4[(size_t)t * 128 + lane * 2];
        float4 xb = x4[(size_t)t * 128 + lane * 2 + 1];
        if (t > 0) {
            const float4* src = (const float4*)(ys + (size_t)(t - 1) * UNITS) + tid;
            v4f av = poll_load_sc1(src);
            while (bad4(av) && --budget > 0) av = poll_load_sc1(src);
            fabuf[t & 1][tid + (tid >> 3)] = *(const float4*)&av;
        }
        float s[4];
#pragma unroll
        for (int r = 0; r < 4; ++r)
            s[r] = dot4(xa, wx[r][0]) + dot4(xb, wx[r][1]);
        if (t > 0) {
            __syncthreads();
            const float4* ab = &fabuf[t & 1][lane * 9];
#pragma unroll
            for (int k = 0; k < 8; ++k) {
                float4 av = ab[k];
#pragma unroll
                for (int r = 0; r < 4; ++r) s[r] += dot4(av, w[r][k]);
            }
        }
#pragma unroll
        for (int m = 32; m >= 1; m >>= 1)
#pragma unroll
            for (int r = 0; r < 4; ++r) s[r] += __shfl_xor(s[r], m, 64);
        if (lane == 0) {
            v4f o;
#pragma unroll
            for (int r = 0; r < 4; ++r) o[r] = ftanh(s[r] + bav[r]);
            pub_store_dev((float4*)(ys + (size_t)t * UNITS + r0), o);
        }
    }
}

extern "C" void kernel_launch(void* const* d_in, const int* in_sizes, int n_in,
                              void* d_out, int out_size, void* d_ws, size_t ws_size,
                              hipStream_t stream) {
    const float* x   = (const float*)d_in[0];   // (1, 8192, 512)
    const float* waa = (const float*)d_in[1];   // (2048, 2048)
    const float* wax = (const float*)d_in[2];   // (2048, 512)
    const float* ba  = (const float*)d_in[3];   // (2048, 1)
    float* ys = (float*)d_out;                  // (1, 8192, 2048)

    const size_t xin_off = 2048;                // bytes; after cnt area
    const size_t need = xin_off + (size_t)TSTEPS * UNITS * sizeof(float);
    if (ws_size >= need) {
        (void)hipFuncSetAttribute(reinterpret_cast<const void*>(rnn_scan_xcd),
                                  hipFuncAttributeMaxDynamicSharedMemorySize,
                                  SCAN_LDS_BYTES);
        int*   wsi = (int*)d_ws;
        float* xin = (float*)((char*)d_ws + xin_off);
        hipLaunchKernelGGL(zero_ws, dim3(1), dim3(512), 0, stream, wsi);
        // re-poison d_out every launch: (T*U)/4 uint4s, 256 thr/blk
        hipLaunchKernelGGL(poison_ys, dim3((TSTEPS * (size_t)UNITS) / (4 * 256)),
                           dim3(256), 0, stream, (v4u*)ys);
        hipLaunchKernelGGL(xin_gemm, dim3(TSTEPS / GT, UNITS / GU), dim3(256), 0, stream,
                           x, wax, ba, xin);
        hipLaunchKernelGGL(rnn_scan_xcd, dim3(1024), dim3(512), SCAN_LDS_BYTES, stream,
                           waa, xin, ys, wsi);
    } else {
        hipLaunchKernelGGL(rnn_scan_fb, dim3(64), dim3(512), 0, stream,
                           x, waa, wax, ba, ys);
    }
}